// Round 13
// baseline (200.999 us; speedup 1.0000x reference)
//
#include <hip/hip_runtime.h>
#include <math.h>

#define TOTAL_ANCHORS 87296
#define NQ 21824           // TOTAL_ANCHORS/4
#define NTOPK 87040        // anchors in levels 0-3 (level 4 passes through)
#define NSEL 4256
#define NWORDS 67          // ceil(4256/64)
#define NPAD   4288        // 67*64, padded row count for word-major mask
#define MAXROUNDS 4300     // safety cap; progress guarantee => <= NSEL rounds
#define CANDMAX 8192       // per-level candidate buffer (keys with bin >= T)
#define NBIN 32768         // 15-bit bins: (key>>48)&0x7FFF (bit15 of f2s>>16 is const)
#define NSLAB 8            // hist slabs: L0 x4, L1 x2, L2 x1, L3 x1
#define PEND_VEC 3216      // (NPAD*8 + NPAD*4)/16 float4s of pend0+pend1
#define NB 128             // persistent blocks (1024 thr): co-resident on 256 CUs

// ---------- helpers ----------
__device__ __forceinline__ float sigmoidf_(float x) {
    return 1.0f / (1.0f + expf(-x));
}
__device__ __forceinline__ unsigned int f2s(float f) {
    unsigned int u = __float_as_uint(f);
    return u ^ ((u >> 31) ? 0xFFFFFFFFu : 0x80000000u);
}
__device__ __forceinline__ float s2f(unsigned int k) {
    unsigned int u = (k & 0x80000000u) ? (k ^ 0x80000000u) : ~k;
    return __uint_as_float(u);
}
__device__ __forceinline__ float f4e(const float4& v, int j) {
    return (j == 0) ? v.x : ((j == 1) ? v.y : ((j == 2) ? v.z : v.w));
}
__device__ __forceinline__ void level_of(int g, int& lv, int& base, int& W, int& stride) {
    if (g < 65536)      { lv = 0; base = 0;     W = 256; stride = 8;   }
    else if (g < 81920) { lv = 1; base = 65536; W = 128; stride = 16;  }
    else if (g < 86016) { lv = 2; base = 81920; W = 64;  stride = 32;  }
    else if (g < 87040) { lv = 3; base = 86016; W = 32;  stride = 64;  }
    else                { lv = 4; base = 87040; W = 16;  stride = 128; }
}
__device__ __forceinline__ int count_greater(const unsigned long long* A, int n,
                                             unsigned long long x) {
    int lo = 0, hi = n;
    while (lo < hi) { int m = (lo + hi) >> 1; if (A[m] > x) lo = m + 1; else hi = m; }
    return lo;
}

struct InPtrs {
    const float* cls[5];
    const float* reg[5];
    const float* ctn[5];
    const float* scales;
};
struct MPtrs {
    unsigned long long *keys, *cmax2, *cand, *sel, *maskC, *pend0G;
    unsigned int *slab, *thr, *cnt, *pend1G, *bars;
    float *scores, *sarea, *out;
    int *labels, *order, *svalid;
    float4 *boxes, *sbox;
};

// device-scope grid barrier; one counter (own 128B line) per barrier index.
// __threadfence = agent-scope fence (buffer_wbl2 / buffer_inv on gfx950):
// release on arrive, acquire on leave -> cross-XCD L2 coherence is handled.
__device__ __forceinline__ void gsync(unsigned int* bars, int idx) {
    __syncthreads();
    if (threadIdx.x == 0) {
        __threadfence();
        unsigned int a = atomicAdd(&bars[idx * 32], 1u) + 1u;
        if (a < (unsigned int)NB) {
            while (atomicAdd(&bars[idx * 32], 0u) < (unsigned int)NB)
                __builtin_amdgcn_s_sleep(4);
        }
        __threadfence();
    }
    __syncthreads();
}

// barrier counters must be 0 at mega start; mega leaves them at NB, so reset
// each call (stream-ordered; kernel-boundary flush publishes the zeros).
__global__ __launch_bounds__(256) void zerobars_kernel(unsigned int* bars) {
    bars[threadIdx.x] = 0u;   // 256 u32 covers 8 barriers * 32-u32 stride
}

__global__ __launch_bounds__(1024) void mega_kernel(InPtrs in, MPtrs m) {
    __shared__ __align__(16) unsigned char smraw[65536];
    const int tid = threadIdx.x;
    const int bid = blockIdx.x;
    const int gid = bid * 1024 + tid;

    // ================= ph1: cmax (x4 anchors, 8-class group) + zero pend/cnt ==
    for (int i = gid; i < NQ * 10; i += NB * 1024) {
        int cg = i / NQ;
        int t = i - cg * NQ;
        int a0 = t * 4;
        int lv, base, W, stride;
        level_of(a0, lv, base, W, stride);
        (void)stride;
        int p0 = a0 - base;
        int HW = W * W;
        const float* cls = in.cls[lv];
        float4 ct = *(const float4*)&in.ctn[lv][p0];
        float sct0 = sigmoidf_(ct.x), sct1 = sigmoidf_(ct.y);
        float sct2 = sigmoidf_(ct.z), sct3 = sigmoidf_(ct.w);
        int c0 = cg * 8;
        unsigned long long b0 = 0ull, b1 = 0ull, b2 = 0ull, b3 = 0ull;
        #pragma unroll
        for (int k = 0; k < 8; ++k) {
            float4 v = *(const float4*)&cls[(c0 + k) * HW + p0];
            unsigned long long lbl = (unsigned long long)(255 - (c0 + k));
            unsigned long long k0 = ((unsigned long long)f2s(sqrtf(__fmul_rn(sigmoidf_(v.x), sct0))) << 32) | lbl;
            unsigned long long k1 = ((unsigned long long)f2s(sqrtf(__fmul_rn(sigmoidf_(v.y), sct1))) << 32) | lbl;
            unsigned long long k2 = ((unsigned long long)f2s(sqrtf(__fmul_rn(sigmoidf_(v.z), sct2))) << 32) | lbl;
            unsigned long long k3 = ((unsigned long long)f2s(sqrtf(__fmul_rn(sigmoidf_(v.w), sct3))) << 32) | lbl;
            b0 = (k0 > b0) ? k0 : b0;
            b1 = (k1 > b1) ? k1 : b1;
            b2 = (k2 > b2) ? k2 : b2;
            b3 = (k3 > b3) ? k3 : b3;
        }
        unsigned long long* dst = m.cmax2 + (size_t)cg * TOTAL_ANCHORS + a0;
        dst[0] = b0; dst[1] = b1; dst[2] = b2; dst[3] = b3;
    }
    if (gid < PEND_VEC) ((float4*)m.pend0G)[gid] = make_float4(0.f, 0.f, 0.f, 0.f);
    else if (gid < PEND_VEC + 128) m.cnt[gid - PEND_VEC] = 0u;
    gsync(m.bars, 0);

    // ================= ph2: decode2 (reduce cmax2, boxes/keys) ================
    if (gid < NQ) {
        int g0 = gid * 4;
        int lv, base, W, stride;
        level_of(g0, lv, base, W, stride);
        int p0 = g0 - base;
        int HW = W * W;
        unsigned long long mk0 = 0ull, mk1 = 0ull, mk2 = 0ull, mk3 = 0ull;
        #pragma unroll
        for (int cg = 0; cg < 10; ++cg) {
            const ulonglong2* s2 = (const ulonglong2*)(m.cmax2 + (size_t)cg * TOTAL_ANCHORS + g0);
            ulonglong2 va = s2[0], vb = s2[1];
            mk0 = (va.x > mk0) ? va.x : mk0;
            mk1 = (va.y > mk1) ? va.y : mk1;
            mk2 = (vb.x > mk2) ? vb.x : mk2;
            mk3 = (vb.y > mk3) ? vb.y : mk3;
        }
        unsigned long long mk[4] = {mk0, mk1, mk2, mk3};
        float scale = in.scales[lv];
        float fs = (float)stride;
        const float* rg = in.reg[lv];
        float4 rq0 = *(const float4*)&rg[0 * HW + p0];
        float4 rq1 = *(const float4*)&rg[1 * HW + p0];
        float4 rq2 = *(const float4*)&rg[2 * HW + p0];
        float4 rq3 = *(const float4*)&rg[3 * HW + p0];
        float4 sc4; int4 lb4;
        #pragma unroll
        for (int j = 0; j < 4; ++j) {
            int p = p0 + j;
            int x = p & (W - 1);
            int y = p / W;
            float best = s2f((unsigned int)(mk[j] >> 32));
            int lbl = 255 - (int)(mk[j] & 0xFFull);
            float r0 = __fmul_rn(fmaxf(__fmul_rn(f4e(rq0, j), scale), 0.0f), fs);
            float r1 = __fmul_rn(fmaxf(__fmul_rn(f4e(rq1, j), scale), 0.0f), fs);
            float r2 = __fmul_rn(fmaxf(__fmul_rn(f4e(rq2, j), scale), 0.0f), fs);
            float r3 = __fmul_rn(fmaxf(__fmul_rn(f4e(rq3, j), scale), 0.0f), fs);
            float ax = __fmul_rn(__fadd_rn((float)x, 0.5f), fs);
            float ay = __fmul_rn(__fadd_rn((float)y, 0.5f), fs);
            float4 b;
            b.x = __fsub_rn(ax, r0);
            b.y = __fsub_rn(ay, r1);
            b.z = __fadd_rn(ax, r2);
            b.w = __fadd_rn(ay, r3);
            m.boxes[g0 + j] = b;
            m.keys[g0 + j] = (mk[j] & 0xFFFFFFFF00000000ull)
                           | (unsigned long long)(unsigned int)(~(unsigned int)p);
            if (j == 0) { sc4.x = best; lb4.x = lbl; }
            else if (j == 1) { sc4.y = best; lb4.y = lbl; }
            else if (j == 2) { sc4.z = best; lb4.z = lbl; }
            else { sc4.w = best; lb4.w = lbl; }
        }
        *(float4*)&m.scores[g0] = sc4;
        *(int4*)&m.labels[g0] = lb4;
    }
    gsync(m.bars, 1);

    // ================= ph3: hist (8 blocks, private LDS) ======================
    if (bid < NSLAB) {
        unsigned int* h = (unsigned int*)smraw;          // [NBIN/2] = 64 KB
        const int starts[NSLAB] = {0, 16384, 32768, 49152, 65536, 73728, 81920, 86016};
        const int ends[NSLAB]   = {16384, 32768, 49152, 65536, 73728, 81920, 86016, 87040};
        for (int i = tid; i < NBIN / 2; i += 1024) h[i] = 0u;
        __syncthreads();
        const int s = starts[bid], e = ends[bid];
        for (int i = s + tid; i < e; i += 1024) {
            unsigned int bin = (unsigned int)(m.keys[i] >> 48) & 0x7FFFu;
            atomicAdd(&h[bin >> 1], 1u << ((bin & 1u) << 4));
        }
        __syncthreads();
        unsigned int* outp = m.slab + bid * (NBIN / 2);
        for (int i = tid; i < NBIN / 2; i += 1024) outp[i] = h[i];
    }
    gsync(m.bars, 2);

    // ================= ph4: select (4 blocks) =================================
    if (bid < 4) {
        const int lvl = bid;
        const int slabS[4] = {0, 4, 6, 7};
        const int slabE[4] = {4, 6, 7, 8};
        unsigned int* csum = (unsigned int*)smraw;       // [1024]
        unsigned int s = 0;
        for (int sb = slabS[lvl]; sb < slabE[lvl]; ++sb) {
            const unsigned int* A = m.slab + sb * (NBIN / 2);
            #pragma unroll 4
            for (int w = tid * 16; w < tid * 16 + 16; ++w) {
                unsigned int v = A[w];
                s += (v & 0xFFFFu) + (v >> 16);
            }
        }
        csum[tid] = s;
        __syncthreads();
        for (int off = 1; off < 1024; off <<= 1) {
            unsigned int v = csum[tid] + ((tid + off < 1024) ? csum[tid + off] : 0u);
            __syncthreads();
            csum[tid] = v;
            __syncthreads();
        }
        unsigned int incl = csum[tid];
        unsigned int incl1 = (tid == 1023) ? 0u : csum[tid + 1];
        if (incl >= 1000u && incl1 < 1000u) {
            unsigned int running = incl1;
            for (int b = tid * 32 + 31; b >= tid * 32; --b) {
                unsigned int c = 0;
                for (int sb = slabS[lvl]; sb < slabE[lvl]; ++sb) {
                    unsigned int v = m.slab[sb * (NBIN / 2) + (b >> 1)];
                    c += (v >> ((b & 1) << 4)) & 0xFFFFu;
                }
                running += c;
                if (running >= 1000u) { m.thr[lvl] = (unsigned int)b; break; }
            }
        }
    }
    gsync(m.bars, 3);

    // ================= ph5: gather (85 blocks, one atomic each) ===============
    if (bid < 85) {
        unsigned int* woff = (unsigned int*)smraw;       // [17]
        int g = gid;                                     // 85*1024 == 87040
        int lvl;
        if (g < 65536)      lvl = 0;
        else if (g < 81920) lvl = 1;
        else if (g < 86016) lvl = 2;
        else                lvl = 3;
        unsigned long long k = m.keys[g];
        bool pass = (((unsigned int)(k >> 48)) & 0x7FFFu) >= m.thr[lvl];
        const int wave = tid >> 6, lane = tid & 63;
        unsigned long long mm = __ballot(pass);
        if (lane == 0) woff[wave] = (unsigned int)__popcll(mm);
        __syncthreads();
        if (tid == 0) {
            unsigned int tot = 0;
            #pragma unroll
            for (int w = 0; w < 16; ++w) { unsigned int c = woff[w]; woff[w] = tot; tot += c; }
            woff[16] = atomicAdd(&m.cnt[lvl << 5], tot);
        }
        __syncthreads();
        if (pass) {
            unsigned int pos = woff[16] + woff[wave]
                             + (unsigned int)__popcll(mm & ((1ull << lane) - 1ull));
            if (pos < CANDMAX) m.cand[(lvl << 13) + pos] = k;  // nondet order; sort fixes
        }
    }
    gsync(m.bars, 4);

    // ================= ph6: finalsort (4 blocks, bitonic) =====================
    if (bid < 4) {
        const int lvl = bid;
        unsigned long long* sk = (unsigned long long*)smraw;   // [CANDMAX] = 64 KB
        int n = (int)m.cnt[lvl << 5];
        if (n > CANDMAX) n = CANDMAX;
        int P = 1024;
        while (P < n) P <<= 1;
        for (int i = tid; i < P; i += 1024)
            sk[i] = (i < n) ? m.cand[(lvl << 13) + i] : 0ull;
        __syncthreads();
        for (int kk = 2; kk <= P; kk <<= 1) {
            for (int j = kk >> 1; j > 0; j >>= 1) {
                for (int i = tid; i < P; i += 1024) {
                    int ixj = i ^ j;
                    if (ixj > i) {
                        unsigned long long a = sk[i], b = sk[ixj];
                        bool sw = ((i & kk) == 0) ? (a < b) : (a > b);
                        if (sw) { sk[i] = b; sk[ixj] = a; }
                    }
                }
                __syncthreads();
            }
        }
        if (tid < 1000) m.sel[lvl * 1000 + tid] = sk[tid];
    }
    gsync(m.bars, 5);

    // ================= ph7: finrank (5 blocks) ================================
    if (bid < 5) {
        unsigned long long* eL  = (unsigned long long*)smraw;           // [NSEL]
        unsigned long long* sk4 = (unsigned long long*)(smraw + 34048); // [256]
        int gown = 0; float scown = 0.f; int vown = 0;
        #pragma unroll
        for (int k = 0; k < 5; ++k) {
            int pos = tid + k * 1024;
            if (pos < NSEL) {
                int g;
                if (pos < 4000) {
                    int lvp = pos / 1000;
                    const int offs_[4] = {0, 65536, 81920, 86016};
                    unsigned long long key = m.sel[pos];
                    unsigned int p = ~((unsigned int)(key & 0xFFFFFFFFull));
                    g = offs_[lvp] + (int)p;
                } else {
                    g = 87040 + (pos - 4000);   // level 4: raw order
                }
                float sc = m.scores[g];
                int valid = (sc >= 0.05f) ? 1 : 0;
                float effs = valid ? sc : -INFINITY;   // suffix-monotone per chunk
                eL[pos] = ((unsigned long long)f2s(effs) << 32) | (unsigned int)(~(unsigned int)pos);
                if (k == bid) { gown = g; scown = sc; vown = valid; }
            }
        }
        __syncthreads();
        if (tid < 256) sk4[tid] = eL[4000 + tid];
        __syncthreads();
        for (int kk = 2; kk <= 256; kk <<= 1) {
            for (int j = kk >> 1; j > 0; j >>= 1) {
                if (tid < 256) {
                    int ixj = tid ^ j;
                    if (ixj > tid) {
                        unsigned long long a = sk4[tid], b = sk4[ixj];
                        bool sw = ((tid & kk) == 0) ? (a < b) : (a > b);
                        if (sw) { sk4[tid] = b; sk4[ixj] = a; }
                    }
                }
                __syncthreads();
            }
        }
        int pos = bid * 1024 + tid;
        if (pos < NSEL) {
            int lb = m.labels[gown];
            float4 bx = m.boxes[gown];
            const float inv = 1.0f / 2048.0f;   // /2048 == *2^-11 exactly
            float4 o4;
            o4.x = fminf(fmaxf(__fmul_rn(bx.x, inv), 0.0f), 1.0f);
            o4.y = fminf(fmaxf(__fmul_rn(bx.y, inv), 0.0f), 1.0f);
            o4.z = fminf(fmaxf(__fmul_rn(bx.z, inv), 0.0f), 1.0f);
            o4.w = fminf(fmaxf(__fmul_rn(bx.w, inv), 0.0f), 1.0f);
            *(float4*)&m.out[pos * 4] = o4;
            m.out[17024 + pos] = scown;
            m.out[21280 + pos] = (float)lb;
            m.out[25536 + pos] = 0.0f;          // keep default; sweep sets kept=1
            float off = __fmul_rn((float)lb, 100000.0f);
            float4 eb;
            eb.x = __fadd_rn(bx.x, off); eb.y = __fadd_rn(bx.y, off);
            eb.z = __fadd_rn(bx.z, off); eb.w = __fadd_rn(bx.w, off);
            float area = __fmul_rn(__fsub_rn(eb.z, eb.x), __fsub_rn(eb.w, eb.y));
            unsigned long long x = eL[pos];
            int rank = count_greater(eL,        1000, x)
                     + count_greater(eL + 1000, 1000, x)
                     + count_greater(eL + 2000, 1000, x)
                     + count_greater(eL + 3000, 1000, x)
                     + count_greater(sk4,        256, x);
            m.order[rank]  = pos;
            m.sbox[rank]   = eb;
            m.sarea[rank]  = area;
            m.svalid[rank] = vown;
        }
    }
    gsync(m.bars, 6);

    // ================= ph8: mask + pend init (wave-triangular) ================
    {
        float4* cbuf = (float4*)smraw;                   // [16][64] = 16 KB
        float*  cav  = (float*)(smraw + 16384);          // [16][64] = 4 KB
        const int wv = tid >> 6, lane = tid & 63;
        const int gw = bid * 16 + wv;                    // 0..2047
        for (int t = gw; t < (NWORDS * (NWORDS + 1)) / 2; t += NB * 16) {
            int r = (int)((sqrtf(8.0f * (float)t + 1.0f) - 1.0f) * 0.5f);
            while ((r + 1) * (r + 2) / 2 <= t) ++r;
            while (r * (r + 1) / 2 > t) --r;
            int c = t - r * (r + 1) / 2;                 // colTile c <= rowTile r
            int col0 = c * 64;
            int cc = col0 + lane;
            float4 cbx; float car; int vcol = 0;
            if (cc < NSEL) { cbx = m.sbox[cc]; car = m.sarea[cc]; vcol = m.svalid[cc]; }
            else { cbx = make_float4(0.f, 0.f, 0.f, 0.f); car = 0.f; }
            cbuf[wv * 64 + lane] = cbx;
            cav[wv * 64 + lane] = car;
            unsigned long long unkw = __ballot(vcol != 0);
            // within-wave LDS write -> cross-lane read: drain LDS queue
            asm volatile("s_waitcnt lgkmcnt(0)" ::: "memory");
            int i = r * 64 + lane;                       // i < NPAD always
            unsigned long long bits = 0ull;
            if (i < NSEL) {
                float4 b = m.sbox[i];
                float ar = m.sarea[i];
                for (int j = 0; j < 64; ++j) {
                    float4 cj = cbuf[wv * 64 + j];
                    float caj = cav[wv * 64 + j];
                    float xx1 = fmaxf(b.x, cj.x);
                    float yy1 = fmaxf(b.y, cj.y);
                    float xx2 = fminf(b.z, cj.z);
                    float yy2 = fminf(b.w, cj.w);
                    float w = fmaxf(1e-10f, __fsub_rn(xx2, xx1));
                    float h = fmaxf(1e-10f, __fsub_rn(yy2, yy1));
                    float inter = __fmul_rn(w, h);
                    float denom = __fadd_rn(__fsub_rn(__fadd_rn(ar, caj), inter), 1e-14f);
                    float ovr = __fdiv_rn(inter, denom);
                    if (ovr > 0.6f) bits |= (1ull << j);
                }
            }
            m.maskC[(size_t)c * NPAD + i] = bits;
            if (c < r && i < NSEL && (bits & unkw)) {
                if (c < 64) atomicOr(&m.pend0G[i], 1ull << c);
                else        atomicOr(&m.pend1G[i], 1u << (c - 64));
            }
        }
    }
    gsync(m.bars, 7);

    // ================= ph9: sweep (block 0 only, incremental fixed point) =====
    if (bid == 0) {
        unsigned long long* keptL = (unsigned long long*)smraw;   // [67]
        unsigned long long* unkL  = keptL + 68;
        unsigned long long* nk    = keptL + 136;
        unsigned long long* nkC   = keptL + 204;
        unsigned long long* ndC   = keptL + 272;
        unsigned long long* cm0s  = keptL + 340;
        unsigned int* cm1s = (unsigned int*)(keptL + 341);
        int* anych = (int*)(cm1s + 1);
        int* wflag = (int*)(cm1s + 2);                            // [16]
        const int lane = tid & 63;
        const int wave = tid >> 6;

        unsigned long long md[5], pend0[5];
        unsigned int pendH[5];
        #pragma unroll
        for (int k = 0; k < 5; ++k) {
            int b = wave + 16 * k;
            unsigned long long w = 0ull;
            md[k] = 0ull; pend0[k] = 0ull; pendH[k] = 0u;
            if (b < NWORDS) {
                int c = b * 64 + lane;
                int v = (c < NSEL) ? m.svalid[c] : 0;
                w = __ballot(v != 0);
                md[k]    = m.maskC[(size_t)b * NPAD + c];
                pend0[k] = m.pend0G[c];
                pendH[k] = m.pend1G[c];
                if (lane == 0) { unkL[b] = w; keptL[b] = 0ull; nk[b] = 0ull; }
            }
        }
        if (tid == 0) { *cm0s = 0ull; *cm1s = 0u; }
        __syncthreads();

        for (int round = 0; round < MAXROUNDS; ++round) {
            unsigned long long cm0 = *cm0s;
            unsigned int cm1 = *cm1s;
            #pragma unroll
            for (int k = 0; k < 5; ++k) {
                int b = wave + 16 * k;
                bool kp = false, dec = false;
                if (b < NWORDS) {
                    int c = b * 64 + lane;
                    unsigned long long uw = unkL[b];
                    if ((uw >> lane) & 1ull) {
                        bool rem = false;
                        unsigned long long todo = pend0[k] & cm0;
                        while (todo) {
                            int w = __ffsll((long long)todo) - 1;
                            todo &= todo - 1ull;
                            unsigned long long mm = m.maskC[(size_t)w * NPAD + c];
                            if (mm & nk[w]) { rem = true; break; }
                            if ((mm & unkL[w]) == 0ull) pend0[k] &= ~(1ull << w);
                        }
                        if (!rem) {
                            unsigned int todoH = pendH[k] & cm1;
                            while (todoH) {
                                int bit = __ffs(todoH) - 1;
                                todoH &= todoH - 1u;
                                int w = 64 + bit;
                                unsigned long long mm = m.maskC[(size_t)w * NPAD + c];
                                if (mm & nk[w]) { rem = true; break; }
                                if ((mm & unkL[w]) == 0ull) pendH[k] &= ~(1u << bit);
                            }
                        }
                        unsigned long long below = (1ull << lane) - 1ull;
                        if (!rem && (md[k] & keptL[b] & below)) rem = true;
                        if (!rem && pend0[k] == 0ull && pendH[k] == 0u
                                 && (md[k] & uw & below) == 0ull) kp = true;
                        dec = rem || kp;
                    }
                }
                unsigned long long kb = __ballot(kp);
                unsigned long long db = __ballot(dec);
                if (b < NWORDS && lane == 0) { nkC[b] = kb; ndC[b] = db; }
            }
            __syncthreads();
            int any = 0;
            #pragma unroll
            for (int k = 0; k < 5; ++k) {
                int b = wave + 16 * k;
                if (b >= NWORDS) continue;
                unsigned long long db = ndC[b];
                if (lane == 0) {
                    keptL[b] |= nkC[b];
                    unkL[b]  &= ~db;
                    nk[b]     = nkC[b];
                }
                any |= (db != 0ull) ? 1 : 0;
            }
            if (lane == 0) wflag[wave] = any;
            __syncthreads();
            if (tid == 0) {
                unsigned long long c0 = 0ull; unsigned int c1 = 0u; int a = 0;
                for (int w = 0; w < 64; ++w) if (ndC[w]) c0 |= (1ull << w);
                for (int w = 64; w < NWORDS; ++w) if (ndC[w]) c1 |= (1u << (w - 64));
                #pragma unroll
                for (int w = 0; w < 16; ++w) a |= wflag[w];
                *cm0s = c0; *cm1s = c1; *anych = a;
            }
            __syncthreads();
            if (!*anych) break;
        }

        #pragma unroll
        for (int k = 0; k < 5; ++k) {
            int b = wave + 16 * k;
            if (b >= NWORDS) continue;
            int c = b * 64 + lane;
            if (c < NSEL && ((keptL[b] >> lane) & 1ull))
                m.out[25536 + m.order[c]] = 1.0f;
        }
    }
}

// ---------- workspace layout (all 16B-aligned) ----------
constexpr size_t OFF_KEYS    = 0;                            // u64 * 87296
constexpr size_t OFF_SCORES  = OFF_KEYS    + 698368;         // f32 * 87296
constexpr size_t OFF_LABELS  = OFF_SCORES  + 349184;         // i32 * 87296
constexpr size_t OFF_BOXES   = OFF_LABELS  + 349184;         // f32x4 * 87296
constexpr size_t OFF_SEL     = OFF_BOXES   + 1396736;        // u64 * 4000
constexpr size_t OFF_ORDER   = OFF_SEL     + 32000;          // i32 * 4256
constexpr size_t OFF_SBOX    = OFF_ORDER   + 17024;          // f32x4 * 4256
constexpr size_t OFF_SAREA   = OFF_SBOX    + 68096;          // f32 * 4256
constexpr size_t OFF_SVALID  = OFF_SAREA   + 17024;          // i32 * 4256
constexpr size_t OFF_MASK    = OFF_SVALID  + 17024;          // u64 * NWORDS * NPAD
constexpr size_t OFF_CMAX2   = OFF_MASK    + (size_t)NWORDS * NPAD * 8;  // u64 * 10 * 87296
constexpr size_t OFF_CNT     = OFF_CMAX2   + 10u * 698368u;  // u32, 4 counters @128B stride
constexpr size_t OFF_PEND0   = OFF_CNT     + 512;            // u64 * NPAD
constexpr size_t OFF_PEND1   = OFF_PEND0   + (size_t)NPAD * 8;  // u32 * NPAD
constexpr size_t OFF_THR     = OFF_PEND1   + (size_t)NPAD * 4;  // u32 * 4
constexpr size_t OFF_SLAB    = OFF_THR     + 64;             // u32 * NSLAB * 16384
constexpr size_t OFF_CAND    = OFF_SLAB    + (size_t)NSLAB * 16384u * 4u;  // u64 * 4 * CANDMAX
constexpr size_t OFF_BARS    = OFF_CAND    + 4u * CANDMAX * 8u;  // u32 * 256 (8 barriers x 32)

extern "C" void kernel_launch(void* const* d_in, const int* in_sizes, int n_in,
                              void* d_out, int out_size, void* d_ws, size_t ws_size,
                              hipStream_t stream) {
    (void)in_sizes; (void)n_in; (void)out_size; (void)ws_size;
    InPtrs P;
    for (int lv = 0; lv < 5; ++lv) {
        P.cls[lv] = (const float*)d_in[3 * lv + 0];
        P.reg[lv] = (const float*)d_in[3 * lv + 1];
        P.ctn[lv] = (const float*)d_in[3 * lv + 2];
    }
    P.scales = (const float*)d_in[15];

    char* ws = (char*)d_ws;
    MPtrs M;
    M.keys   = (unsigned long long*)(ws + OFF_KEYS);
    M.scores = (float*)             (ws + OFF_SCORES);
    M.labels = (int*)               (ws + OFF_LABELS);
    M.boxes  = (float4*)            (ws + OFF_BOXES);
    M.sel    = (unsigned long long*)(ws + OFF_SEL);
    M.order  = (int*)               (ws + OFF_ORDER);
    M.sbox   = (float4*)            (ws + OFF_SBOX);
    M.sarea  = (float*)             (ws + OFF_SAREA);
    M.svalid = (int*)               (ws + OFF_SVALID);
    M.maskC  = (unsigned long long*)(ws + OFF_MASK);
    M.cmax2  = (unsigned long long*)(ws + OFF_CMAX2);
    M.cnt    = (unsigned int*)      (ws + OFF_CNT);
    M.pend0G = (unsigned long long*)(ws + OFF_PEND0);
    M.pend1G = (unsigned int*)      (ws + OFF_PEND1);
    M.thr    = (unsigned int*)      (ws + OFF_THR);
    M.slab   = (unsigned int*)      (ws + OFF_SLAB);
    M.cand   = (unsigned long long*)(ws + OFF_CAND);
    M.bars   = (unsigned int*)      (ws + OFF_BARS);
    M.out    = (float*)d_out;

    zerobars_kernel<<<1, 256, 0, stream>>>(M.bars);
    mega_kernel<<<NB, 1024, 0, stream>>>(P, M);
}

// Round 14
// 143.583 us; speedup vs baseline: 1.3999x; 1.3999x over previous
//
#include <hip/hip_runtime.h>
#include <math.h>

#define TOTAL_ANCHORS 87296
#define NTOPK 87040        // anchors in levels 0-3 (level 4 passes through)
#define NSEL 4256
#define NWORDS 67          // ceil(4256/64)
#define NPAD   4288        // 67*64, padded row count for word-major mask
#define MAXROUNDS 4300     // safety cap; progress guarantee => <= NSEL rounds
#define CANDCAP 8190       // LDS candidate capacity ((64KB-16)/8)
#define NBIN 32768         // 15-bit bins: (key>>48)&0x7FFF (bit15 of f2s>>16 is const)
#define NSLAB 8            // hist slabs: L0 x4, L1 x2, L2 x1, L3 x1
#define PEND_VEC 3216      // (NPAD*8 + NPAD*4)/16 float4s of pend0+pend1

// ---------- helpers ----------
__device__ __forceinline__ float sigmoidf_(float x) {
    return 1.0f / (1.0f + expf(-x));
}
// monotone float->uint mapping (ascending)
__device__ __forceinline__ unsigned int f2s(float f) {
    unsigned int u = __float_as_uint(f);
    return u ^ ((u >> 31) ? 0xFFFFFFFFu : 0x80000000u);
}
__device__ __forceinline__ float s2f(unsigned int k) {
    unsigned int u = (k & 0x80000000u) ? (k ^ 0x80000000u) : ~k;
    return __uint_as_float(u);
}
__device__ __forceinline__ void level_of(int g, int& lv, int& base, int& W, int& stride) {
    if (g < 65536)      { lv = 0; base = 0;     W = 256; stride = 8;   }
    else if (g < 81920) { lv = 1; base = 65536; W = 128; stride = 16;  }
    else if (g < 86016) { lv = 2; base = 81920; W = 64;  stride = 32;  }
    else if (g < 87040) { lv = 3; base = 86016; W = 32;  stride = 64;  }
    else                { lv = 4; base = 87040; W = 16;  stride = 128; }
}

struct InPtrs {
    const float* cls[5];
    const float* reg[5];
    const float* ctn[5];
    const float* scales;
};

// ---------- 1a. cmax: grid-parallel class argmax, NO atomics ----------
// Each (anchor, class-group) writes its own slot cmax2[cg][a]; decode2 reduces
// the 10 slots in-register. 7 MB round-trip stays in L2. No zero-init needed.
__global__ __launch_bounds__(256) void cmax_kernel(InPtrs in,
        unsigned long long* __restrict__ cmax2) {
    int a = blockIdx.x * 256 + threadIdx.x;      // 341*256 == 87296 exactly
    int cg = blockIdx.y;                         // 10 groups of 8 classes
    int lv, base, W, stride;
    level_of(a, lv, base, W, stride);
    (void)stride;
    int p = a - base;
    int HW = W * W;
    const float* cls = in.cls[lv];
    float sctn = sigmoidf_(in.ctn[lv][p]);
    int c0 = cg * 8;
    float v[8];
    #pragma unroll
    for (int k = 0; k < 8; ++k) v[k] = cls[(c0 + k) * HW + p];
    unsigned long long best = 0ull;
    #pragma unroll
    for (int k = 0; k < 8; ++k) {
        float pr = sqrtf(__fmul_rn(sigmoidf_(v[k]), sctn));
        unsigned long long key = ((unsigned long long)f2s(pr) << 32)
                               | (unsigned long long)(255 - (c0 + k));
        best = (key > best) ? key : best;
    }
    cmax2[(size_t)cg * TOTAL_ANCHORS + a] = best;   // coalesced plain store
}

// ---------- 1b. decode2: reduce cmax2, decode boxes/keys (NO atomics) ---------
__global__ __launch_bounds__(256) void decode2_kernel(InPtrs in,
        const unsigned long long* __restrict__ cmax2,
        unsigned long long* __restrict__ keys, float* __restrict__ scores,
        int* __restrict__ labels, float4* __restrict__ boxes) {
    int g = blockIdx.x * 256 + threadIdx.x;
    int lv, base, W, stride;
    level_of(g, lv, base, W, stride);
    int p = g - base;
    int HW = W * W;
    int x = p & (W - 1);
    int y = p / W;
    unsigned long long mk = 0ull;
    #pragma unroll
    for (int cg = 0; cg < 10; ++cg) {
        unsigned long long v = cmax2[(size_t)cg * TOTAL_ANCHORS + g];
        mk = (v > mk) ? v : mk;
    }
    float best = s2f((unsigned int)(mk >> 32));
    int lbl = 255 - (int)(mk & 0xFFull);
    float scale = in.scales[lv];
    float fs = (float)stride;
    const float* rg = in.reg[lv];
    float r0 = __fmul_rn(fmaxf(__fmul_rn(rg[0 * HW + p], scale), 0.0f), fs);
    float r1 = __fmul_rn(fmaxf(__fmul_rn(rg[1 * HW + p], scale), 0.0f), fs);
    float r2 = __fmul_rn(fmaxf(__fmul_rn(rg[2 * HW + p], scale), 0.0f), fs);
    float r3 = __fmul_rn(fmaxf(__fmul_rn(rg[3 * HW + p], scale), 0.0f), fs);
    float ax = __fmul_rn(__fadd_rn((float)x, 0.5f), fs);
    float ay = __fmul_rn(__fadd_rn((float)y, 0.5f), fs);
    float4 b;
    b.x = __fsub_rn(ax, r0);
    b.y = __fsub_rn(ay, r1);
    b.z = __fadd_rn(ax, r2);
    b.w = __fadd_rn(ay, r3);
    scores[g] = best;
    labels[g] = lbl;
    boxes[g]  = b;
    keys[g] = (mk & 0xFFFFFFFF00000000ull)
            | (unsigned long long)(unsigned int)(~(unsigned int)p);
}

// ---------- 2a. hist: 8 blocks, private LDS histogram -> non-atomic slabs -----
__global__ __launch_bounds__(1024) void hist_kernel(
        const unsigned long long* __restrict__ keys,
        unsigned int* __restrict__ slab) {
    __shared__ unsigned int h[NBIN / 2];         // 64 KB
    const int starts[NSLAB] = {0, 16384, 32768, 49152, 65536, 73728, 81920, 86016};
    const int ends[NSLAB]   = {16384, 32768, 49152, 65536, 73728, 81920, 86016, 87040};
    const int tid = threadIdx.x;
    for (int i = tid; i < NBIN / 2; i += 1024) h[i] = 0u;
    __syncthreads();
    const int s = starts[blockIdx.x], e = ends[blockIdx.x];
    for (int i = s + tid; i < e; i += 1024) {
        unsigned int bin = (unsigned int)(keys[i] >> 48) & 0x7FFFu;
        atomicAdd(&h[bin >> 1], 1u << ((bin & 1u) << 4));
    }
    __syncthreads();
    unsigned int* out = slab + blockIdx.x * (NBIN / 2);
    for (int i = tid; i < NBIN / 2; i += 1024) out[i] = h[i];
}

// ---------- 2b. topksel: fused select + gather + sort, one block per level ----
// All block-local: suffix-scan own slabs -> threshold (LDS), gather own level's
// keys straight into LDS (wave-aggregated LDS counter, no global atomics),
// in-place bitonic sort, write top-1000. Replaces 3 kernels + 2 gaps + the
// cand/cnt/thr global round-trips.
__global__ __launch_bounds__(1024) void topksel_kernel(
        const unsigned long long* __restrict__ keys,
        const unsigned int* __restrict__ slab,
        unsigned long long* __restrict__ sel) {
    const int lvl = blockIdx.x;
    const int tid = threadIdx.x;
    __shared__ __align__(16) unsigned char sm[65536];
    unsigned int* csum = (unsigned int*)sm;                     // select phase
    unsigned int* meta = (unsigned int*)sm;                     // [0]=thr [1]=cnt
    unsigned long long* cand = (unsigned long long*)(sm + 16);  // capacity CANDCAP
    const int slabS[4] = {0, 4, 6, 7};
    const int slabE[4] = {4, 6, 7, 8};
    // ---- select: suffix-scan the level's histogram slabs ----
    unsigned int s = 0;
    for (int sb = slabS[lvl]; sb < slabE[lvl]; ++sb) {
        const unsigned int* A = slab + sb * (NBIN / 2);
        #pragma unroll 4
        for (int w = tid * 16; w < tid * 16 + 16; ++w) {
            unsigned int v = A[w];
            s += (v & 0xFFFFu) + (v >> 16);
        }
    }
    csum[tid] = s;
    __syncthreads();
    for (int off = 1; off < 1024; off <<= 1) {
        unsigned int v = csum[tid] + ((tid + off < 1024) ? csum[tid + off] : 0u);
        __syncthreads();
        csum[tid] = v;
        __syncthreads();
    }
    unsigned int incl = csum[tid];
    unsigned int incl1 = (tid == 1023) ? 0u : csum[tid + 1];
    __syncthreads();                         // all csum reads done before meta writes
    if (tid == 0) meta[1] = 0u;              // gather counter
    if (incl >= 1000u && incl1 < 1000u) {    // unique crossing chunk
        unsigned int running = incl1;
        for (int b = tid * 32 + 31; b >= tid * 32; --b) {
            unsigned int c = 0;
            for (int sb = slabS[lvl]; sb < slabE[lvl]; ++sb) {
                unsigned int v = slab[sb * (NBIN / 2) + (b >> 1)];
                c += (v >> ((b & 1) << 4)) & 0xFFFFu;
            }
            running += c;
            if (running >= 1000u) { meta[0] = (unsigned int)b; break; }
        }
    }
    __syncthreads();
    const unsigned int T = meta[0];
    // ---- gather own level's keys into LDS (wave-aggregated append) ----
    const int startsL[4] = {0, 65536, 81920, 86016};
    const int endsL[4]   = {65536, 81920, 86016, 87040};   // spans all mult. of 1024
    const int lane = tid & 63;
    for (int i = startsL[lvl] + tid; i < endsL[lvl]; i += 1024) {
        unsigned long long k = keys[i];
        bool pass = (((unsigned int)(k >> 48)) & 0x7FFFu) >= T;
        unsigned long long mm = __ballot(pass);
        if (mm) {
            int leader = __ffsll((long long)mm) - 1;
            unsigned int base_ = 0;
            if (lane == leader) base_ = atomicAdd(&meta[1], (unsigned int)__popcll(mm));
            base_ = (unsigned int)__shfl((int)base_, leader);
            if (pass) {
                unsigned int pos = base_ + (unsigned int)__popcll(mm & ((1ull << lane) - 1ull));
                if (pos < CANDCAP) cand[pos] = k;   // nondet order; sort fixes
            }
        }
    }
    __syncthreads();
    // ---- bitonic sort desc in place, emit top-1000 ----
    int n = (int)meta[1];
    if (n > CANDCAP) n = CANDCAP;
    int P = 1024;
    while (P < n) P <<= 1;                    // <= 8192 (cap region allows)
    if (P > CANDCAP) P = 8192;                // pad region clamp (indices < CANDCAP used)
    for (int i = tid; i < P; i += 1024) if (i >= n) { if (i < CANDCAP) cand[i] = 0ull; }
    __syncthreads();
    for (int kk = 2; kk <= P; kk <<= 1) {
        for (int j = kk >> 1; j > 0; j >>= 1) {
            for (int i = tid; i < P; i += 1024) {
                int ixj = i ^ j;
                if (ixj > i && ixj < CANDCAP && i < CANDCAP) {
                    unsigned long long a = cand[i], b = cand[ixj];
                    bool sw = ((i & kk) == 0) ? (a < b) : (a > b);
                    if (sw) { cand[i] = b; cand[ixj] = a; }
                }
            }
            __syncthreads();
        }
    }
    if (tid < 1000) sel[lvl * 1000 + tid] = cand[tid];
}

// ---------- 3a. fin: finalize (grid-parallel) + zero pend for mask ------------
__global__ __launch_bounds__(256) void fin_kernel(
        const unsigned long long* __restrict__ sel,
        const float* __restrict__ scores, const int* __restrict__ labels,
        const float4* __restrict__ boxes, float* __restrict__ out,
        float4* __restrict__ entbox, float* __restrict__ entarea,
        int* __restrict__ entvalid, unsigned long long* __restrict__ ekeyG,
        float4* __restrict__ pendzero) {
    int pos = blockIdx.x * 256 + threadIdx.x;
    if (pos < PEND_VEC) pendzero[pos] = make_float4(0.f, 0.f, 0.f, 0.f);
    if (pos >= NSEL) return;
    int g;
    if (pos < 4000) {
        int lv = pos / 1000;
        const int offs_[4] = {0, 65536, 81920, 86016};
        unsigned long long key = sel[pos];
        unsigned int p = ~((unsigned int)(key & 0xFFFFFFFFull));
        g = offs_[lv] + (int)p;
    } else {
        g = 87040 + (pos - 4000);   // level 4: raw order
    }
    float sc = scores[g];
    int lb = labels[g];
    float4 bx = boxes[g];
    const float inv = 1.0f / 2048.0f;   // /2048 == *2^-11 exactly
    out[pos * 4 + 0] = fminf(fmaxf(__fmul_rn(bx.x, inv), 0.0f), 1.0f);
    out[pos * 4 + 1] = fminf(fmaxf(__fmul_rn(bx.y, inv), 0.0f), 1.0f);
    out[pos * 4 + 2] = fminf(fmaxf(__fmul_rn(bx.z, inv), 0.0f), 1.0f);
    out[pos * 4 + 3] = fminf(fmaxf(__fmul_rn(bx.w, inv), 0.0f), 1.0f);
    out[17024 + pos] = sc;
    out[21280 + pos] = (float)lb;
    out[25536 + pos] = 0.0f;            // keep default; sweep sets kept=1
    float off = __fmul_rn((float)lb, 100000.0f);
    float4 eb;
    eb.x = __fadd_rn(bx.x, off); eb.y = __fadd_rn(bx.y, off);
    eb.z = __fadd_rn(bx.z, off); eb.w = __fadd_rn(bx.w, off);
    entbox[pos] = eb;
    entarea[pos] = __fmul_rn(__fsub_rn(eb.z, eb.x), __fsub_rn(eb.w, eb.y));
    int valid = (sc >= 0.05f) ? 1 : 0;
    entvalid[pos] = valid;
    float effs = valid ? sc : -INFINITY;  // suffix-monotone per sorted chunk
    ekeyG[pos] = ((unsigned long long)f2s(effs) << 32) | (unsigned int)(~(unsigned int)pos);
}

// ---------- 3b. rank: merge-rank across 5 blocks (ekey chunks in LDS) ---------
__device__ __forceinline__ int count_greater(const unsigned long long* A, int n,
                                             unsigned long long x) {
    int lo = 0, hi = n;
    while (lo < hi) { int m = (lo + hi) >> 1; if (A[m] > x) lo = m + 1; else hi = m; }
    return lo;
}
__global__ __launch_bounds__(1024) void rank_kernel(
        const unsigned long long* __restrict__ ekeyG,
        const float4* __restrict__ entbox, const float* __restrict__ entarea,
        const int* __restrict__ entvalid,
        int* __restrict__ order, float4* __restrict__ sbox,
        float* __restrict__ sarea, int* __restrict__ svalid) {
    __shared__ unsigned long long eL[4000];
    __shared__ unsigned long long sk4[256];
    const int tid = threadIdx.x;
    for (int i = tid; i < 4000; i += 1024) eL[i] = ekeyG[i];
    if (tid < 256) sk4[tid] = ekeyG[4000 + tid];
    __syncthreads();
    // redundant per-block bitonic sort of the 256 level-4 keys (desc)
    for (int kk = 2; kk <= 256; kk <<= 1) {
        for (int j = kk >> 1; j > 0; j >>= 1) {
            if (tid < 256) {
                int ixj = tid ^ j;
                if (ixj > tid) {
                    unsigned long long a = sk4[tid], b = sk4[ixj];
                    bool sw = ((tid & kk) == 0) ? (a < b) : (a > b);
                    if (sw) { sk4[tid] = b; sk4[ixj] = a; }
                }
            }
            __syncthreads();
        }
    }
    int pos = blockIdx.x * 1024 + tid;
    if (pos < NSEL) {
        unsigned long long x = (pos < 4000) ? eL[pos] : ekeyG[pos];
        int rank = count_greater(eL,        1000, x)
                 + count_greater(eL + 1000, 1000, x)
                 + count_greater(eL + 2000, 1000, x)
                 + count_greater(eL + 3000, 1000, x)
                 + count_greater(sk4,        256, x);
        order[rank]  = pos;
        sbox[rank]   = entbox[pos];
        sarea[rank]  = entarea[pos];
        svalid[rank] = entvalid[pos];
    }
}

// ---------- 4. IoU bitmask + PEND init (round-1 matvec fused in) ----------
__global__ __launch_bounds__(64) void mask_kernel(
        const float4* __restrict__ sbox, const float* __restrict__ sarea,
        const int* __restrict__ svalid,
        unsigned long long* __restrict__ maskC,
        unsigned long long* __restrict__ pend0G,
        unsigned int* __restrict__ pend1G) {
    int colTile = blockIdx.x, rowTile = blockIdx.y;
    if (colTile > rowTile) return;
    __shared__ float4 cb[64];
    __shared__ float ca[64];
    int tid = threadIdx.x;
    int col0 = colTile * 64;
    int c = col0 + tid;
    int vcol = 0;
    if (c < NSEL) { cb[tid] = sbox[c]; ca[tid] = sarea[c]; vcol = svalid[c]; }
    else { cb[tid] = make_float4(0.f, 0.f, 0.f, 0.f); ca[tid] = 0.f; }
    unsigned long long unkw = __ballot(vcol != 0);   // initial unknowns of word colTile
    __syncthreads();
    int i = rowTile * 64 + tid;
    unsigned long long bits = 0ull;
    if (i < NSEL) {
        float4 b = sbox[i];
        float ar = sarea[i];
        for (int j = 0; j < 64; ++j) {
            float xx1 = fmaxf(b.x, cb[j].x);
            float yy1 = fmaxf(b.y, cb[j].y);
            float xx2 = fminf(b.z, cb[j].z);
            float yy2 = fminf(b.w, cb[j].w);
            float w = fmaxf(1e-10f, __fsub_rn(xx2, xx1));
            float h = fmaxf(1e-10f, __fsub_rn(yy2, yy1));
            float inter = __fmul_rn(w, h);
            float denom = __fadd_rn(__fsub_rn(__fadd_rn(ar, ca[j]), inter), 1e-14f);
            float ovr = __fdiv_rn(inter, denom);
            if (ovr > 0.6f) bits |= (1ull << j);
        }
    }
    maskC[(size_t)colTile * NPAD + i] = bits;   // coalesced; pad rows store 0
    // pend init: strictly-earlier words only (diagonal handled in-register in sweep)
    if (colTile < rowTile && i < NSEL && (bits & unkw)) {
        if (colTile < 64) atomicOr(&pend0G[i], 1ull << colTile);
        else              atomicOr(&pend1G[i], 1u << (colTile - 64));
    }
}

// ---------- 5. greedy sweep: INCREMENTAL fixed point ----------
__global__ __launch_bounds__(1024) void sweep_kernel(
        const unsigned long long* __restrict__ maskC,
        const unsigned long long* __restrict__ pend0G,
        const unsigned int* __restrict__ pend1G,
        const int* __restrict__ order, const int* __restrict__ svalid,
        float* __restrict__ out_keep) {
    const int tid = threadIdx.x;
    const int lane = tid & 63;
    const int wave = tid >> 6;
    __shared__ unsigned long long keptL[NWORDS], unkL[NWORDS];
    __shared__ unsigned long long nk[NWORDS], nkC[NWORDS], ndC[NWORDS];
    __shared__ unsigned long long cm0s;
    __shared__ unsigned int cm1s;
    __shared__ int anych;
    __shared__ int wflag[16];

    unsigned long long md[5], pend0[5];
    unsigned int pendH[5];
    #pragma unroll
    for (int k = 0; k < 5; ++k) {
        int b = wave + 16 * k;
        unsigned long long w = 0ull;
        md[k] = 0ull; pend0[k] = 0ull; pendH[k] = 0u;
        if (b < NWORDS) {
            int c = b * 64 + lane;
            int v = (c < NSEL) ? svalid[c] : 0;
            w = __ballot(v != 0);
            md[k]    = maskC[(size_t)b * NPAD + c];
            pend0[k] = pend0G[c];
            pendH[k] = pend1G[c];
            if (lane == 0) { unkL[b] = w; keptL[b] = 0ull; nk[b] = 0ull; }
        }
    }
    if (tid == 0) { cm0s = 0ull; cm1s = 0u; }
    __syncthreads();

    for (int round = 0; round < MAXROUNDS; ++round) {
        unsigned long long cm0 = cm0s;
        unsigned int cm1 = cm1s;
        // ---- compute phase ----
        #pragma unroll
        for (int k = 0; k < 5; ++k) {
            int b = wave + 16 * k;
            bool kp = false, dec = false;
            if (b < NWORDS) {
                int c = b * 64 + lane;
                unsigned long long uw = unkL[b];
                if ((uw >> lane) & 1ull) {
                    bool rem = false;
                    unsigned long long todo = pend0[k] & cm0;
                    while (todo) {
                        int w = __ffsll((long long)todo) - 1;
                        todo &= todo - 1ull;
                        unsigned long long m = maskC[(size_t)w * NPAD + c];
                        if (m & nk[w]) { rem = true; break; }
                        if ((m & unkL[w]) == 0ull) pend0[k] &= ~(1ull << w);
                    }
                    if (!rem) {
                        unsigned int todoH = pendH[k] & cm1;
                        while (todoH) {
                            int bit = __ffs(todoH) - 1;
                            todoH &= todoH - 1u;
                            int w = 64 + bit;
                            unsigned long long m = maskC[(size_t)w * NPAD + c];
                            if (m & nk[w]) { rem = true; break; }
                            if ((m & unkL[w]) == 0ull) pendH[k] &= ~(1u << bit);
                        }
                    }
                    unsigned long long below = (1ull << lane) - 1ull;
                    if (!rem && (md[k] & keptL[b] & below)) rem = true;
                    if (!rem && pend0[k] == 0ull && pendH[k] == 0u
                             && (md[k] & uw & below) == 0ull) kp = true;
                    dec = rem || kp;
                }
            }
            unsigned long long kb = __ballot(kp);
            unsigned long long db = __ballot(dec);
            if (b < NWORDS && lane == 0) { nkC[b] = kb; ndC[b] = db; }
        }
        __syncthreads();
        // ---- commit phase (each wave owns its words) ----
        int any = 0;
        #pragma unroll
        for (int k = 0; k < 5; ++k) {
            int b = wave + 16 * k;
            if (b >= NWORDS) continue;
            unsigned long long db = ndC[b];
            if (lane == 0) {
                keptL[b] |= nkC[b];
                unkL[b]  &= ~db;
                nk[b]     = nkC[b];
            }
            any |= (db != 0ull) ? 1 : 0;
        }
        if (lane == 0) wflag[wave] = any;
        __syncthreads();
        if (tid == 0) {
            unsigned long long c0 = 0ull; unsigned int c1 = 0u; int a = 0;
            for (int w = 0; w < 64; ++w) if (ndC[w]) c0 |= (1ull << w);
            for (int w = 64; w < NWORDS; ++w) if (ndC[w]) c1 |= (1u << (w - 64));
            #pragma unroll
            for (int w = 0; w < 16; ++w) a |= wflag[w];
            cm0s = c0; cm1s = c1; anych = a;
        }
        __syncthreads();
        if (!anych) break;
    }

    #pragma unroll
    for (int k = 0; k < 5; ++k) {
        int b = wave + 16 * k;
        if (b >= NWORDS) continue;
        int c = b * 64 + lane;
        if (c < NSEL && ((keptL[b] >> lane) & 1ull)) out_keep[order[c]] = 1.0f;
    }
}

// ---------- workspace layout (all 16B-aligned) ----------
constexpr size_t OFF_KEYS    = 0;                            // u64 * 87296
constexpr size_t OFF_SCORES  = OFF_KEYS    + 698368;         // f32 * 87296
constexpr size_t OFF_LABELS  = OFF_SCORES  + 349184;         // i32 * 87296
constexpr size_t OFF_BOXES   = OFF_LABELS  + 349184;         // f32x4 * 87296
constexpr size_t OFF_SEL     = OFF_BOXES   + 1396736;        // u64 * 4000
constexpr size_t OFF_ORDER   = OFF_SEL     + 32000;          // i32 * 4256
constexpr size_t OFF_SBOX    = OFF_ORDER   + 17024;          // f32x4 * 4256
constexpr size_t OFF_SAREA   = OFF_SBOX    + 68096;          // f32 * 4256
constexpr size_t OFF_SVALID  = OFF_SAREA   + 17024;          // i32 * 4256
constexpr size_t OFF_MASK    = OFF_SVALID  + 17024;          // u64 * NWORDS * NPAD
constexpr size_t OFF_CMAX2   = OFF_MASK    + (size_t)NWORDS * NPAD * 8;  // u64 * 10 * 87296
constexpr size_t OFF_PEND0   = OFF_CMAX2   + 10u * 698368u;  // u64 * NPAD
constexpr size_t OFF_PEND1   = OFF_PEND0   + (size_t)NPAD * 8;  // u32 * NPAD
constexpr size_t OFF_SLAB    = OFF_PEND1   + (size_t)NPAD * 4;  // u32 * NSLAB * 16384
constexpr size_t OFF_EKEY    = OFF_SLAB    + (size_t)NSLAB * 16384u * 4u;  // u64 * 4256
constexpr size_t OFF_ENTBOX  = OFF_EKEY    + 34048;          // f32x4 * 4256
constexpr size_t OFF_ENTAREA = OFF_ENTBOX  + 68096;          // f32 * 4256
constexpr size_t OFF_ENTVAL  = OFF_ENTAREA + 17024;          // i32 * 4256

extern "C" void kernel_launch(void* const* d_in, const int* in_sizes, int n_in,
                              void* d_out, int out_size, void* d_ws, size_t ws_size,
                              hipStream_t stream) {
    (void)in_sizes; (void)n_in; (void)out_size; (void)ws_size;
    InPtrs P;
    for (int lv = 0; lv < 5; ++lv) {
        P.cls[lv] = (const float*)d_in[3 * lv + 0];
        P.reg[lv] = (const float*)d_in[3 * lv + 1];
        P.ctn[lv] = (const float*)d_in[3 * lv + 2];
    }
    P.scales = (const float*)d_in[15];

    char* ws = (char*)d_ws;
    unsigned long long* keys   = (unsigned long long*)(ws + OFF_KEYS);
    float*              scores = (float*)             (ws + OFF_SCORES);
    int*                labels = (int*)               (ws + OFF_LABELS);
    float4*             boxes  = (float4*)            (ws + OFF_BOXES);
    unsigned long long* sel    = (unsigned long long*)(ws + OFF_SEL);
    int*                order  = (int*)               (ws + OFF_ORDER);
    float4*             sbox   = (float4*)            (ws + OFF_SBOX);
    float*              sarea  = (float*)             (ws + OFF_SAREA);
    int*                svalid = (int*)               (ws + OFF_SVALID);
    unsigned long long* maskb  = (unsigned long long*)(ws + OFF_MASK);
    unsigned long long* cmax2  = (unsigned long long*)(ws + OFF_CMAX2);
    unsigned long long* pend0  = (unsigned long long*)(ws + OFF_PEND0);
    unsigned int*       pend1  = (unsigned int*)      (ws + OFF_PEND1);
    unsigned int*       slab   = (unsigned int*)      (ws + OFF_SLAB);
    unsigned long long* ekeyG  = (unsigned long long*)(ws + OFF_EKEY);
    float4*             entbox = (float4*)            (ws + OFF_ENTBOX);
    float*              entarea= (float*)             (ws + OFF_ENTAREA);
    int*                entval = (int*)               (ws + OFF_ENTVAL);
    float* out = (float*)d_out;

    cmax_kernel<<<dim3(341, 10), 256, 0, stream>>>(P, cmax2);
    decode2_kernel<<<341, 256, 0, stream>>>(P, cmax2, keys, scores, labels, boxes);
    hist_kernel<<<NSLAB, 1024, 0, stream>>>(keys, slab);
    topksel_kernel<<<4, 1024, 0, stream>>>(keys, slab, sel);
    fin_kernel<<<(NSEL + 255) / 256, 256, 0, stream>>>(sel, scores, labels, boxes, out,
                                                       entbox, entarea, entval, ekeyG,
                                                       (float4*)(ws + OFF_PEND0));
    rank_kernel<<<(NSEL + 1023) / 1024, 1024, 0, stream>>>(ekeyG, entbox, entarea, entval,
                                                           order, sbox, sarea, svalid);
    mask_kernel<<<dim3(NWORDS, NWORDS), 64, 0, stream>>>(sbox, sarea, svalid,
                                                         maskb, pend0, pend1);
    sweep_kernel<<<1, 1024, 0, stream>>>(maskb, pend0, pend1, order, svalid, out + 25536);
}

// Round 15
// 119.146 us; speedup vs baseline: 1.6870x; 1.2051x over previous
//
#include <hip/hip_runtime.h>
#include <math.h>

#define TOTAL_ANCHORS 87296
#define NTOPK 87040        // anchors in levels 0-3 (level 4 passes through)
#define NSEL 4256
#define NWORDS 67          // ceil(4256/64)
#define NPAD   4288        // 67*64, padded row count for word-major mask
#define MAXROUNDS 4300     // safety cap; progress guarantee => <= NSEL rounds
#define CANDMAX 8192       // per-level candidate buffer (keys with bin >= T)
#define NBIN 32768         // 15-bit bins: (key>>48)&0x7FFF (bit15 of f2s>>16 is const)
#define NSLAB 8            // hist slabs: L0 x4, L1 x2, L2 x1, L3 x1
#define PEND_VEC 3216      // (NPAD*8 + NPAD*4)/16 float4s of pend0+pend1

// ---------- helpers ----------
__device__ __forceinline__ float sigmoidf_(float x) {
    return 1.0f / (1.0f + expf(-x));
}
// monotone float->uint mapping (ascending)
__device__ __forceinline__ unsigned int f2s(float f) {
    unsigned int u = __float_as_uint(f);
    return u ^ ((u >> 31) ? 0xFFFFFFFFu : 0x80000000u);
}
__device__ __forceinline__ float s2f(unsigned int k) {
    unsigned int u = (k & 0x80000000u) ? (k ^ 0x80000000u) : ~k;
    return __uint_as_float(u);
}
__device__ __forceinline__ void level_of(int g, int& lv, int& base, int& W, int& stride) {
    if (g < 65536)      { lv = 0; base = 0;     W = 256; stride = 8;   }
    else if (g < 81920) { lv = 1; base = 65536; W = 128; stride = 16;  }
    else if (g < 86016) { lv = 2; base = 81920; W = 64;  stride = 32;  }
    else if (g < 87040) { lv = 3; base = 86016; W = 32;  stride = 64;  }
    else                { lv = 4; base = 87040; W = 16;  stride = 128; }
}

struct InPtrs {
    const float* cls[5];
    const float* reg[5];
    const float* ctn[5];
    const float* scales;
};

// ---------- 1a. cmax: grid-parallel class argmax, NO atomics ----------
__global__ __launch_bounds__(256) void cmax_kernel(InPtrs in,
        unsigned long long* __restrict__ cmax2) {
    int a = blockIdx.x * 256 + threadIdx.x;      // 341*256 == 87296 exactly
    int cg = blockIdx.y;                         // 10 groups of 8 classes
    int lv, base, W, stride;
    level_of(a, lv, base, W, stride);
    (void)stride;
    int p = a - base;
    int HW = W * W;
    const float* cls = in.cls[lv];
    float sctn = sigmoidf_(in.ctn[lv][p]);
    int c0 = cg * 8;
    float v[8];
    #pragma unroll
    for (int k = 0; k < 8; ++k) v[k] = cls[(c0 + k) * HW + p];
    unsigned long long best = 0ull;
    #pragma unroll
    for (int k = 0; k < 8; ++k) {
        float pr = sqrtf(__fmul_rn(sigmoidf_(v[k]), sctn));
        unsigned long long key = ((unsigned long long)f2s(pr) << 32)
                               | (unsigned long long)(255 - (c0 + k));
        best = (key > best) ? key : best;
    }
    cmax2[(size_t)cg * TOTAL_ANCHORS + a] = best;   // coalesced plain store
}

// ---------- 1b. decode2: reduce cmax2, decode boxes/keys (NO atomics) ---------
__global__ __launch_bounds__(256) void decode2_kernel(InPtrs in,
        const unsigned long long* __restrict__ cmax2,
        unsigned long long* __restrict__ keys, float* __restrict__ scores,
        int* __restrict__ labels, float4* __restrict__ boxes) {
    int g = blockIdx.x * 256 + threadIdx.x;
    int lv, base, W, stride;
    level_of(g, lv, base, W, stride);
    int p = g - base;
    int HW = W * W;
    int x = p & (W - 1);
    int y = p / W;
    unsigned long long mk = 0ull;
    #pragma unroll
    for (int cg = 0; cg < 10; ++cg) {
        unsigned long long v = cmax2[(size_t)cg * TOTAL_ANCHORS + g];
        mk = (v > mk) ? v : mk;
    }
    float best = s2f((unsigned int)(mk >> 32));
    int lbl = 255 - (int)(mk & 0xFFull);
    float scale = in.scales[lv];
    float fs = (float)stride;
    const float* rg = in.reg[lv];
    float r0 = __fmul_rn(fmaxf(__fmul_rn(rg[0 * HW + p], scale), 0.0f), fs);
    float r1 = __fmul_rn(fmaxf(__fmul_rn(rg[1 * HW + p], scale), 0.0f), fs);
    float r2 = __fmul_rn(fmaxf(__fmul_rn(rg[2 * HW + p], scale), 0.0f), fs);
    float r3 = __fmul_rn(fmaxf(__fmul_rn(rg[3 * HW + p], scale), 0.0f), fs);
    float ax = __fmul_rn(__fadd_rn((float)x, 0.5f), fs);
    float ay = __fmul_rn(__fadd_rn((float)y, 0.5f), fs);
    float4 b;
    b.x = __fsub_rn(ax, r0);
    b.y = __fsub_rn(ay, r1);
    b.z = __fadd_rn(ax, r2);
    b.w = __fadd_rn(ay, r3);
    scores[g] = best;
    labels[g] = lbl;
    boxes[g]  = b;
    keys[g] = (mk & 0xFFFFFFFF00000000ull)
            | (unsigned long long)(unsigned int)(~(unsigned int)p);
}

// ---------- 2a. hist: 8 blocks, private LDS histogram -> non-atomic slabs -----
// Block 0 additionally zeroes the gather counters (stream-ordered before gatsel).
__global__ __launch_bounds__(1024) void hist_kernel(
        const unsigned long long* __restrict__ keys,
        unsigned int* __restrict__ slab, unsigned int* __restrict__ cnt) {
    __shared__ unsigned int h[NBIN / 2];         // 64 KB
    const int starts[NSLAB] = {0, 16384, 32768, 49152, 65536, 73728, 81920, 86016};
    const int ends[NSLAB]   = {16384, 32768, 49152, 65536, 73728, 81920, 86016, 87040};
    const int tid = threadIdx.x;
    if (blockIdx.x == 0 && tid < 128) cnt[tid] = 0u;
    for (int i = tid; i < NBIN / 2; i += 1024) h[i] = 0u;
    __syncthreads();
    const int s = starts[blockIdx.x], e = ends[blockIdx.x];
    for (int i = s + tid; i < e; i += 1024) {
        unsigned int bin = (unsigned int)(keys[i] >> 48) & 0x7FFFu;
        atomicAdd(&h[bin >> 1], 1u << ((bin & 1u) << 4));
    }
    __syncthreads();
    unsigned int* out = slab + blockIdx.x * (NBIN / 2);
    for (int i = tid; i < NBIN / 2; i += 1024) out[i] = h[i];
}

// ---------- 2b. gatsel: fused select+gather, 85 blocks (full width kept) ------
// Each block REDUNDANTLY computes its level's threshold (suffix-scan of the
// level's slabs, parallel across blocks) then gathers its own 1024-key range
// with the wave-aggregated block atomic. Removes the select launch + thr trip.
__global__ __launch_bounds__(1024) void gatsel_kernel(
        const unsigned long long* __restrict__ keys,
        const unsigned int* __restrict__ slab,
        unsigned long long* __restrict__ cand, unsigned int* __restrict__ cnt) {
    const int tid = threadIdx.x;
    int g = blockIdx.x * 1024 + tid;             // 85*1024 == 87040 exactly
    int lvl;
    if (g < 65536)      lvl = 0;
    else if (g < 81920) lvl = 1;
    else if (g < 86016) lvl = 2;
    else                lvl = 3;                  // block-uniform (ranges % 1024 == 0)
    const int slabS[4] = {0, 4, 6, 7};
    const int slabE[4] = {4, 6, 7, 8};
    __shared__ unsigned int csum[1024];
    __shared__ unsigned int Ts;
    // ---- redundant select: suffix-scan this level's histogram slabs ----
    unsigned int s = 0;
    for (int sb = slabS[lvl]; sb < slabE[lvl]; ++sb) {
        const unsigned int* A = slab + sb * (NBIN / 2);
        #pragma unroll 4
        for (int w = tid * 16; w < tid * 16 + 16; ++w) {   // 32 bins = 16 words
            unsigned int v = A[w];
            s += (v & 0xFFFFu) + (v >> 16);
        }
    }
    csum[tid] = s;
    __syncthreads();
    for (int off = 1; off < 1024; off <<= 1) {
        unsigned int v = csum[tid] + ((tid + off < 1024) ? csum[tid + off] : 0u);
        __syncthreads();
        csum[tid] = v;
        __syncthreads();
    }
    unsigned int incl = csum[tid];
    unsigned int incl1 = (tid == 1023) ? 0u : csum[tid + 1];
    if (incl >= 1000u && incl1 < 1000u) {                // unique crossing chunk
        unsigned int running = incl1;
        for (int b = tid * 32 + 31; b >= tid * 32; --b) {
            unsigned int c = 0;
            for (int sb = slabS[lvl]; sb < slabE[lvl]; ++sb) {
                unsigned int v = slab[sb * (NBIN / 2) + (b >> 1)];
                c += (v >> ((b & 1) << 4)) & 0xFFFFu;
            }
            running += c;
            if (running >= 1000u) { Ts = (unsigned int)b; break; }
        }
    }
    __syncthreads();
    const unsigned int T = Ts;
    // ---- gather (round-11 form: one global atomic per block) ----
    unsigned long long k = keys[g];
    bool pass = (((unsigned int)(k >> 48)) & 0x7FFFu) >= T;
    __shared__ unsigned int woff[16];
    __shared__ unsigned int base_;
    const int wave = tid >> 6, lane = tid & 63;
    unsigned long long m = __ballot(pass);
    if (lane == 0) woff[wave] = (unsigned int)__popcll(m);
    __syncthreads();
    if (tid == 0) {
        unsigned int tot = 0;
        #pragma unroll
        for (int w = 0; w < 16; ++w) { unsigned int c = woff[w]; woff[w] = tot; tot += c; }
        base_ = atomicAdd(&cnt[lvl << 5], tot);
    }
    __syncthreads();
    if (pass) {
        unsigned int pos = base_ + woff[wave]
                         + (unsigned int)__popcll(m & ((1ull << lane) - 1ull));
        if (pos < CANDMAX) cand[(lvl << 13) + pos] = k;  // order nondet; sort fixes
    }
}

// ---------- 2c. finalsort: bitonic-sort candidates desc, take top-1000 --------
__global__ __launch_bounds__(1024) void finalsort_kernel(
        const unsigned long long* __restrict__ cand,
        const unsigned int* __restrict__ cnt,
        unsigned long long* __restrict__ sel) {
    const int lvl = blockIdx.x;
    const int tid = threadIdx.x;
    __shared__ unsigned long long sk[CANDMAX];
    int n = (int)cnt[lvl << 5];
    if (n > CANDMAX) n = CANDMAX;
    int P = 1024;
    while (P < n) P <<= 1;                     // <= 8192
    for (int i = tid; i < P; i += 1024)
        sk[i] = (i < n) ? cand[(lvl << 13) + i] : 0ull;   // 0 sinks (real keys > 0)
    __syncthreads();
    for (int kk = 2; kk <= P; kk <<= 1) {
        for (int j = kk >> 1; j > 0; j >>= 1) {
            for (int i = tid; i < P; i += 1024) {
                int ixj = i ^ j;
                if (ixj > i) {
                    unsigned long long a = sk[i], b = sk[ixj];
                    bool sw = ((i & kk) == 0) ? (a < b) : (a > b);
                    if (sw) { sk[i] = b; sk[ixj] = a; }
                }
            }
            __syncthreads();
        }
    }
    if (tid < 1000) sel[lvl * 1000 + tid] = sk[tid];
}

// ---------- 3a. fin: finalize (grid-parallel) + zero pend for mask ------------
__global__ __launch_bounds__(256) void fin_kernel(
        const unsigned long long* __restrict__ sel,
        const float* __restrict__ scores, const int* __restrict__ labels,
        const float4* __restrict__ boxes, float* __restrict__ out,
        float4* __restrict__ entbox, float* __restrict__ entarea,
        int* __restrict__ entvalid, unsigned long long* __restrict__ ekeyG,
        float4* __restrict__ pendzero) {
    int pos = blockIdx.x * 256 + threadIdx.x;
    if (pos < PEND_VEC) pendzero[pos] = make_float4(0.f, 0.f, 0.f, 0.f);
    if (pos >= NSEL) return;
    int g;
    if (pos < 4000) {
        int lv = pos / 1000;
        const int offs_[4] = {0, 65536, 81920, 86016};
        unsigned long long key = sel[pos];
        unsigned int p = ~((unsigned int)(key & 0xFFFFFFFFull));
        g = offs_[lv] + (int)p;
    } else {
        g = 87040 + (pos - 4000);   // level 4: raw order
    }
    float sc = scores[g];
    int lb = labels[g];
    float4 bx = boxes[g];
    const float inv = 1.0f / 2048.0f;   // /2048 == *2^-11 exactly
    out[pos * 4 + 0] = fminf(fmaxf(__fmul_rn(bx.x, inv), 0.0f), 1.0f);
    out[pos * 4 + 1] = fminf(fmaxf(__fmul_rn(bx.y, inv), 0.0f), 1.0f);
    out[pos * 4 + 2] = fminf(fmaxf(__fmul_rn(bx.z, inv), 0.0f), 1.0f);
    out[pos * 4 + 3] = fminf(fmaxf(__fmul_rn(bx.w, inv), 0.0f), 1.0f);
    out[17024 + pos] = sc;
    out[21280 + pos] = (float)lb;
    out[25536 + pos] = 0.0f;            // keep default; sweep sets kept=1
    float off = __fmul_rn((float)lb, 100000.0f);
    float4 eb;
    eb.x = __fadd_rn(bx.x, off); eb.y = __fadd_rn(bx.y, off);
    eb.z = __fadd_rn(bx.z, off); eb.w = __fadd_rn(bx.w, off);
    entbox[pos] = eb;
    entarea[pos] = __fmul_rn(__fsub_rn(eb.z, eb.x), __fsub_rn(eb.w, eb.y));
    int valid = (sc >= 0.05f) ? 1 : 0;
    entvalid[pos] = valid;
    float effs = valid ? sc : -INFINITY;  // suffix-monotone per sorted chunk
    ekeyG[pos] = ((unsigned long long)f2s(effs) << 32) | (unsigned int)(~(unsigned int)pos);
}

// ---------- 3b. rank: merge-rank across 5 blocks (ekey chunks in LDS) ---------
__device__ __forceinline__ int count_greater(const unsigned long long* A, int n,
                                             unsigned long long x) {
    int lo = 0, hi = n;
    while (lo < hi) { int m = (lo + hi) >> 1; if (A[m] > x) lo = m + 1; else hi = m; }
    return lo;
}
__global__ __launch_bounds__(1024) void rank_kernel(
        const unsigned long long* __restrict__ ekeyG,
        const float4* __restrict__ entbox, const float* __restrict__ entarea,
        const int* __restrict__ entvalid,
        int* __restrict__ order, float4* __restrict__ sbox,
        float* __restrict__ sarea, int* __restrict__ svalid) {
    __shared__ unsigned long long eL[4000];
    __shared__ unsigned long long sk4[256];
    const int tid = threadIdx.x;
    for (int i = tid; i < 4000; i += 1024) eL[i] = ekeyG[i];
    if (tid < 256) sk4[tid] = ekeyG[4000 + tid];
    __syncthreads();
    // redundant per-block bitonic sort of the 256 level-4 keys (desc)
    for (int kk = 2; kk <= 256; kk <<= 1) {
        for (int j = kk >> 1; j > 0; j >>= 1) {
            if (tid < 256) {
                int ixj = tid ^ j;
                if (ixj > tid) {
                    unsigned long long a = sk4[tid], b = sk4[ixj];
                    bool sw = ((tid & kk) == 0) ? (a < b) : (a > b);
                    if (sw) { sk4[tid] = b; sk4[ixj] = a; }
                }
            }
            __syncthreads();
        }
    }
    int pos = blockIdx.x * 1024 + tid;
    if (pos < NSEL) {
        unsigned long long x = (pos < 4000) ? eL[pos] : ekeyG[pos];
        int rank = count_greater(eL,        1000, x)
                 + count_greater(eL + 1000, 1000, x)
                 + count_greater(eL + 2000, 1000, x)
                 + count_greater(eL + 3000, 1000, x)
                 + count_greater(sk4,        256, x);
        order[rank]  = pos;
        sbox[rank]   = entbox[pos];
        sarea[rank]  = entarea[pos];
        svalid[rank] = entvalid[pos];
    }
}

// ---------- 4. IoU bitmask + PEND init (round-1 matvec fused in) ----------
__global__ __launch_bounds__(64) void mask_kernel(
        const float4* __restrict__ sbox, const float* __restrict__ sarea,
        const int* __restrict__ svalid,
        unsigned long long* __restrict__ maskC,
        unsigned long long* __restrict__ pend0G,
        unsigned int* __restrict__ pend1G) {
    int colTile = blockIdx.x, rowTile = blockIdx.y;
    if (colTile > rowTile) return;
    __shared__ float4 cb[64];
    __shared__ float ca[64];
    int tid = threadIdx.x;
    int col0 = colTile * 64;
    int c = col0 + tid;
    int vcol = 0;
    if (c < NSEL) { cb[tid] = sbox[c]; ca[tid] = sarea[c]; vcol = svalid[c]; }
    else { cb[tid] = make_float4(0.f, 0.f, 0.f, 0.f); ca[tid] = 0.f; }
    unsigned long long unkw = __ballot(vcol != 0);   // initial unknowns of word colTile
    __syncthreads();
    int i = rowTile * 64 + tid;
    unsigned long long bits = 0ull;
    if (i < NSEL) {
        float4 b = sbox[i];
        float ar = sarea[i];
        for (int j = 0; j < 64; ++j) {
            float xx1 = fmaxf(b.x, cb[j].x);
            float yy1 = fmaxf(b.y, cb[j].y);
            float xx2 = fminf(b.z, cb[j].z);
            float yy2 = fminf(b.w, cb[j].w);
            float w = fmaxf(1e-10f, __fsub_rn(xx2, xx1));
            float h = fmaxf(1e-10f, __fsub_rn(yy2, yy1));
            float inter = __fmul_rn(w, h);
            float denom = __fadd_rn(__fsub_rn(__fadd_rn(ar, ca[j]), inter), 1e-14f);
            float ovr = __fdiv_rn(inter, denom);
            if (ovr > 0.6f) bits |= (1ull << j);
        }
    }
    maskC[(size_t)colTile * NPAD + i] = bits;   // coalesced; pad rows store 0
    // pend init: strictly-earlier words only (diagonal handled in-register in sweep)
    if (colTile < rowTile && i < NSEL && (bits & unkw)) {
        if (colTile < 64) atomicOr(&pend0G[i], 1ull << colTile);
        else              atomicOr(&pend1G[i], 1u << (colTile - 64));
    }
}

// ---------- 5. greedy sweep: INCREMENTAL fixed point ----------
__global__ __launch_bounds__(1024) void sweep_kernel(
        const unsigned long long* __restrict__ maskC,
        const unsigned long long* __restrict__ pend0G,
        const unsigned int* __restrict__ pend1G,
        const int* __restrict__ order, const int* __restrict__ svalid,
        float* __restrict__ out_keep) {
    const int tid = threadIdx.x;
    const int lane = tid & 63;
    const int wave = tid >> 6;
    __shared__ unsigned long long keptL[NWORDS], unkL[NWORDS];
    __shared__ unsigned long long nk[NWORDS], nkC[NWORDS], ndC[NWORDS];
    __shared__ unsigned long long cm0s;
    __shared__ unsigned int cm1s;
    __shared__ int anych;
    __shared__ int wflag[16];

    unsigned long long md[5], pend0[5];
    unsigned int pendH[5];
    #pragma unroll
    for (int k = 0; k < 5; ++k) {
        int b = wave + 16 * k;
        unsigned long long w = 0ull;
        md[k] = 0ull; pend0[k] = 0ull; pendH[k] = 0u;
        if (b < NWORDS) {
            int c = b * 64 + lane;
            int v = (c < NSEL) ? svalid[c] : 0;
            w = __ballot(v != 0);
            md[k]    = maskC[(size_t)b * NPAD + c];
            pend0[k] = pend0G[c];
            pendH[k] = pend1G[c];
            if (lane == 0) { unkL[b] = w; keptL[b] = 0ull; nk[b] = 0ull; }
        }
    }
    if (tid == 0) { cm0s = 0ull; cm1s = 0u; }
    __syncthreads();

    for (int round = 0; round < MAXROUNDS; ++round) {
        unsigned long long cm0 = cm0s;
        unsigned int cm1 = cm1s;
        // ---- compute phase ----
        #pragma unroll
        for (int k = 0; k < 5; ++k) {
            int b = wave + 16 * k;
            bool kp = false, dec = false;
            if (b < NWORDS) {
                int c = b * 64 + lane;
                unsigned long long uw = unkL[b];
                if ((uw >> lane) & 1ull) {
                    bool rem = false;
                    unsigned long long todo = pend0[k] & cm0;
                    while (todo) {
                        int w = __ffsll((long long)todo) - 1;
                        todo &= todo - 1ull;
                        unsigned long long m = maskC[(size_t)w * NPAD + c];
                        if (m & nk[w]) { rem = true; break; }
                        if ((m & unkL[w]) == 0ull) pend0[k] &= ~(1ull << w);
                    }
                    if (!rem) {
                        unsigned int todoH = pendH[k] & cm1;
                        while (todoH) {
                            int bit = __ffs(todoH) - 1;
                            todoH &= todoH - 1u;
                            int w = 64 + bit;
                            unsigned long long m = maskC[(size_t)w * NPAD + c];
                            if (m & nk[w]) { rem = true; break; }
                            if ((m & unkL[w]) == 0ull) pendH[k] &= ~(1u << bit);
                        }
                    }
                    unsigned long long below = (1ull << lane) - 1ull;
                    if (!rem && (md[k] & keptL[b] & below)) rem = true;
                    if (!rem && pend0[k] == 0ull && pendH[k] == 0u
                             && (md[k] & uw & below) == 0ull) kp = true;
                    dec = rem || kp;
                }
            }
            unsigned long long kb = __ballot(kp);
            unsigned long long db = __ballot(dec);
            if (b < NWORDS && lane == 0) { nkC[b] = kb; ndC[b] = db; }
        }
        __syncthreads();
        // ---- commit phase (each wave owns its words) ----
        int any = 0;
        #pragma unroll
        for (int k = 0; k < 5; ++k) {
            int b = wave + 16 * k;
            if (b >= NWORDS) continue;
            unsigned long long db = ndC[b];
            if (lane == 0) {
                keptL[b] |= nkC[b];
                unkL[b]  &= ~db;
                nk[b]     = nkC[b];
            }
            any |= (db != 0ull) ? 1 : 0;
        }
        if (lane == 0) wflag[wave] = any;
        __syncthreads();
        if (tid == 0) {
            unsigned long long c0 = 0ull; unsigned int c1 = 0u; int a = 0;
            for (int w = 0; w < 64; ++w) if (ndC[w]) c0 |= (1ull << w);
            for (int w = 64; w < NWORDS; ++w) if (ndC[w]) c1 |= (1u << (w - 64));
            #pragma unroll
            for (int w = 0; w < 16; ++w) a |= wflag[w];
            cm0s = c0; cm1s = c1; anych = a;
        }
        __syncthreads();
        if (!anych) break;
    }

    #pragma unroll
    for (int k = 0; k < 5; ++k) {
        int b = wave + 16 * k;
        if (b >= NWORDS) continue;
        int c = b * 64 + lane;
        if (c < NSEL && ((keptL[b] >> lane) & 1ull)) out_keep[order[c]] = 1.0f;
    }
}

// ---------- workspace layout (all 16B-aligned) ----------
constexpr size_t OFF_KEYS    = 0;                            // u64 * 87296
constexpr size_t OFF_SCORES  = OFF_KEYS    + 698368;         // f32 * 87296
constexpr size_t OFF_LABELS  = OFF_SCORES  + 349184;         // i32 * 87296
constexpr size_t OFF_BOXES   = OFF_LABELS  + 349184;         // f32x4 * 87296
constexpr size_t OFF_SEL     = OFF_BOXES   + 1396736;        // u64 * 4000
constexpr size_t OFF_ORDER   = OFF_SEL     + 32000;          // i32 * 4256
constexpr size_t OFF_SBOX    = OFF_ORDER   + 17024;          // f32x4 * 4256
constexpr size_t OFF_SAREA   = OFF_SBOX    + 68096;          // f32 * 4256
constexpr size_t OFF_SVALID  = OFF_SAREA   + 17024;          // i32 * 4256
constexpr size_t OFF_MASK    = OFF_SVALID  + 17024;          // u64 * NWORDS * NPAD
constexpr size_t OFF_CMAX2   = OFF_MASK    + (size_t)NWORDS * NPAD * 8;  // u64 * 10 * 87296
constexpr size_t OFF_CNT     = OFF_CMAX2   + 10u * 698368u;  // u32, 4 counters @128B stride
constexpr size_t OFF_PEND0   = OFF_CNT     + 512;            // u64 * NPAD
constexpr size_t OFF_PEND1   = OFF_PEND0   + (size_t)NPAD * 8;  // u32 * NPAD
constexpr size_t OFF_SLAB    = OFF_PEND1   + (size_t)NPAD * 4;  // u32 * NSLAB * 16384
constexpr size_t OFF_CAND    = OFF_SLAB    + (size_t)NSLAB * 16384u * 4u;  // u64 * 4 * CANDMAX
constexpr size_t OFF_EKEY    = OFF_CAND    + 4u * CANDMAX * 8u; // u64 * 4256
constexpr size_t OFF_ENTBOX  = OFF_EKEY    + 34048;          // f32x4 * 4256
constexpr size_t OFF_ENTAREA = OFF_ENTBOX  + 68096;          // f32 * 4256
constexpr size_t OFF_ENTVAL  = OFF_ENTAREA + 17024;          // i32 * 4256

extern "C" void kernel_launch(void* const* d_in, const int* in_sizes, int n_in,
                              void* d_out, int out_size, void* d_ws, size_t ws_size,
                              hipStream_t stream) {
    (void)in_sizes; (void)n_in; (void)out_size; (void)ws_size;
    InPtrs P;
    for (int lv = 0; lv < 5; ++lv) {
        P.cls[lv] = (const float*)d_in[3 * lv + 0];
        P.reg[lv] = (const float*)d_in[3 * lv + 1];
        P.ctn[lv] = (const float*)d_in[3 * lv + 2];
    }
    P.scales = (const float*)d_in[15];

    char* ws = (char*)d_ws;
    unsigned long long* keys   = (unsigned long long*)(ws + OFF_KEYS);
    float*              scores = (float*)             (ws + OFF_SCORES);
    int*                labels = (int*)               (ws + OFF_LABELS);
    float4*             boxes  = (float4*)            (ws + OFF_BOXES);
    unsigned long long* sel    = (unsigned long long*)(ws + OFF_SEL);
    int*                order  = (int*)               (ws + OFF_ORDER);
    float4*             sbox   = (float4*)            (ws + OFF_SBOX);
    float*              sarea  = (float*)             (ws + OFF_SAREA);
    int*                svalid = (int*)               (ws + OFF_SVALID);
    unsigned long long* maskb  = (unsigned long long*)(ws + OFF_MASK);
    unsigned long long* cmax2  = (unsigned long long*)(ws + OFF_CMAX2);
    unsigned int*       cnt    = (unsigned int*)      (ws + OFF_CNT);
    unsigned long long* pend0  = (unsigned long long*)(ws + OFF_PEND0);
    unsigned int*       pend1  = (unsigned int*)      (ws + OFF_PEND1);
    unsigned int*       slab   = (unsigned int*)      (ws + OFF_SLAB);
    unsigned long long* cand   = (unsigned long long*)(ws + OFF_CAND);
    unsigned long long* ekeyG  = (unsigned long long*)(ws + OFF_EKEY);
    float4*             entbox = (float4*)            (ws + OFF_ENTBOX);
    float*              entarea= (float*)             (ws + OFF_ENTAREA);
    int*                entval = (int*)               (ws + OFF_ENTVAL);
    float* out = (float*)d_out;

    cmax_kernel<<<dim3(341, 10), 256, 0, stream>>>(P, cmax2);
    decode2_kernel<<<341, 256, 0, stream>>>(P, cmax2, keys, scores, labels, boxes);
    hist_kernel<<<NSLAB, 1024, 0, stream>>>(keys, slab, cnt);
    gatsel_kernel<<<85, 1024, 0, stream>>>(keys, slab, cand, cnt);
    finalsort_kernel<<<4, 1024, 0, stream>>>(cand, cnt, sel);
    fin_kernel<<<(NSEL + 255) / 256, 256, 0, stream>>>(sel, scores, labels, boxes, out,
                                                       entbox, entarea, entval, ekeyG,
                                                       (float4*)(ws + OFF_PEND0));
    rank_kernel<<<(NSEL + 1023) / 1024, 1024, 0, stream>>>(ekeyG, entbox, entarea, entval,
                                                           order, sbox, sarea, svalid);
    mask_kernel<<<dim3(NWORDS, NWORDS), 64, 0, stream>>>(sbox, sarea, svalid,
                                                         maskb, pend0, pend1);
    sweep_kernel<<<1, 1024, 0, stream>>>(maskb, pend0, pend1, order, svalid, out + 25536);
}